// Round 8
// baseline (132.514 us; speedup 1.0000x reference)
//
#include <hip/hip_runtime.h>
#include <stdint.h>

#define T_LEN 524288
#define SEG 8
#define WARM 8
#define EPC (SEG + WARM + 1)   // 17 staged (t,x) entries per chain
#define CHAINS 16
#define GSP (CHAINS * SEG)     // 128 spikes per wave sub-group
#define NCH 512                // chunks (1024 t each)

typedef short short8 __attribute__((ext_vector_type(8)));
typedef float f4 __attribute__((ext_vector_type(4)));
#define KEEPA(v) asm volatile("" : "+v"(v))

// ---- workspace layout (bytes) ----
static const size_t OFF_CNT  = 0;          // 512 int
static const size_t OFF_FLAG = 4096;       // 1024 int (pairs)
static const size_t OFF_SPK  = 16384;      // 512*1024 int (chunk-local spike times)

__device__ __forceinline__ short bfr(float f) {        // fp32 -> bf16 RNE
    uint32_t u = __float_as_uint(f);
    u = (u + 0x7fffu + ((u >> 16) & 1u)) >> 16;
    return (short)u;
}

// padded LDS index: +1 word per 32 -> lane-stride-4 accesses are 2 lanes/bank (free)
#define IDX(j) ((j) + ((j) >> 5))

// poison-proof flag pair: f2 = ~f1, a single fill constant can never match both
__device__ __forceinline__ int flagval(int c, int which) {
    int v = 0x51AB7E3D ^ (int)((unsigned)c * 2654435761u);
    return which ? ~v : v;
}
__device__ __forceinline__ void waitflag(int* flags, int c) {
    const int e1 = flagval(c, 0), e2 = flagval(c, 1);
    while (__hip_atomic_load(&flags[2 * c],     __ATOMIC_RELAXED, __HIP_MEMORY_SCOPE_AGENT) != e1 ||
           __hip_atomic_load(&flags[2 * c + 1], __ATOMIC_RELAXED, __HIP_MEMORY_SCOPE_AGENT) != e2)
        __builtin_amdgcn_s_sleep(2);
}

struct MaskSM  { float tile[1190]; float cs2[1190]; float wsum[4]; int wtot[4]; };
struct ChainSM { float2 st[4][CHAINS * EPC]; unsigned hx[4][CHAINS * 20]; float ab[4][2 * GSP]; };
union  SMU     { MaskSM m; ChainSM c; };

// ---- single fused kernel: block b masks chunk b, chains chunk b-1 ----
// Cross-block deps point strictly BACKWARD (flags b-5..b-1) -> deadlock-free
// under in-order dispatch at any residency (no co-residency assumption).
__global__ __launch_bounds__(256)
void k_all(const float* __restrict__ x,  const float* __restrict__ Wih,
           const float* __restrict__ Whh, const float* __restrict__ bih,
           const float* __restrict__ bhh, const float* __restrict__ Wv,
           const float* __restrict__ bv,  const float* __restrict__ Wsc,
           const float* __restrict__ bs,  float* __restrict__ out, int out_size,
           int* __restrict__ cnt, int* __restrict__ spk, int* __restrict__ flags)
{
    __shared__ SMU sm;
    __shared__ int s_fs;                    // first spike time of OWN chunk b
    const int b = blockIdx.x;
    const int tid = threadIdx.x;
    const int lane = tid & 63, w4 = tid >> 6;

    if (tid == 0) s_fs = T_LEN;

    // ================= phase A: mask + local scatter for chunk b =================
    if (b < NCH) {
        const int bs_ = b * 1024;
        for (int j = tid; j < 1154; j += 256) {
            int g = bs_ - 130 + j;
            sm.m.tile[IDX(j)] = (g >= 0) ? x[g] : 0.f;
        }
        __syncthreads();

        const int j0 = tid * 5;
        float p[5]; float run = 0.f;
        #pragma unroll
        for (int k = 0; k < 5; ++k) {
            float v = (j0 + k < 1154) ? sm.m.tile[IDX(j0 + k)] : 0.f;
            run = fmaf(v, v, run);
            p[k] = run;
        }
        float incl = run;
        for (int d = 1; d < 64; d <<= 1) {
            float u = __shfl_up(incl, d, 64);
            if (lane >= d) incl += u;
        }
        if (lane == 63) sm.m.wsum[w4] = incl;
        __syncthreads();
        float base = incl - run;
        for (int i = 0; i < w4; ++i) base += sm.m.wsum[i];
        #pragma unroll
        for (int k = 0; k < 5; ++k)
            if (j0 + k < 1154) sm.m.cs2[IDX(j0 + k)] = base + p[k];
        __syncthreads();

        const int loc = tid * 4;
        float tv[6];
        #pragma unroll
        for (int q = 0; q < 6; ++q) tv[q] = sm.m.tile[IDX(loc + 128 + q)];
        float4 mf; int mbit[4]; int msum = 0;
        float* fp = &mf.x;
        #pragma unroll
        for (int it = 0; it < 4; ++it) {
            int t = bs_ + loc + it;
            int cdiv = t < 128 ? (t < 1 ? 1 : t) : 128;
            float s = sm.m.cs2[IDX(loc + 129 + it)] - sm.m.cs2[IDX(loc + 1 + it)];
            float rms = sqrtf(fmaxf(s, 0.f) / (float)cdiv) + 1e-8f;
            float xt = tv[it + 2];
            float pr = 2.f * tv[it + 1] - tv[it];
            bool m = (t < 2) || (fabsf(xt - pr) > 2.5f * rms);
            mbit[it] = m ? 1 : 0; fp[it] = m ? 1.f : 0.f; msum += m ? 1 : 0;
        }
        int oi = T_LEN + 1 + bs_ + loc;
        if (oi + 3 < out_size) *(float4*)(out + oi) = mf;

        int e1 = mbit[0], e2 = mbit[0] + mbit[1], e3 = e2 + mbit[2];
        int incs = msum;
        for (int d = 1; d < 64; d <<= 1) {
            int u = __shfl_up(incs, d, 64);
            if (lane >= d) incs += u;
        }
        if (lane == 63) sm.m.wtot[w4] = incs;
        __syncthreads();
        int woff = 0;
        for (int i = 0; i < w4; ++i) woff += sm.m.wtot[i];
        int texcl = woff + incs - msum;
        int ee[4] = {0, e1, e2, e3};
        int* sp = spk + b * 1024 + texcl;
        #pragma unroll
        for (int k = 0; k < 4; ++k)
            if (mbit[k]) sp[ee[k]] = bs_ + loc + k;
        if (msum > 0 && texcl == 0) {       // exactly one thread: the first spiker
            int fk = mbit[0] ? 0 : mbit[1] ? 1 : mbit[2] ? 2 : 3;
            s_fs = bs_ + loc + fk;
        }
        if (tid == 0)
            cnt[b] = sm.m.wtot[0] + sm.m.wtot[1] + sm.m.wtot[2] + sm.m.wtot[3];
        __syncthreads();                    // all spk/cnt stores drained (vmcnt 0)
        if (tid == 0) {
            __threadfence();                // agent release (L2 writeback)
            __hip_atomic_store(&flags[2 * b],     flagval(b, 0), __ATOMIC_RELEASE, __HIP_MEMORY_SCOPE_AGENT);
            __hip_atomic_store(&flags[2 * b + 1], flagval(b, 1), __ATOMIC_RELEASE, __HIP_MEMORY_SCOPE_AGENT);
        }
    }
    if (b == 0) return;

    // ================= phase B: chains for chunk c = b-1 =================
    const int c = b - 1;
    const int lo = (c - 4 > 0) ? c - 4 : 0;
    if (tid == 0) {
        for (int cc = lo; cc <= c; ++cc) waitflag(flags, cc);
        __threadfence();                    // agent acquire (cache inv)
    }
    __syncthreads();                        // union transition + flag visibility

    const int cntc = cnt[c];
    const int baseL = 128 * w4;             // this wave's sub-group of chunk c
    const int m = lane & 15, quad = lane >> 4;

    if (baseL < cntc) {
        float2*   st = sm.c.st[w4];
        unsigned* hx = sm.c.hx[w4];
        float*    ab = sm.c.ab[w4];

        // ---- A fragments (static): A[m][k], k = 8*quad + j ----
        short8 A1[6], A2[6], A3;
        #pragma unroll
        for (int t = 0; t < 6; ++t) {
            union { short s[8]; short8 v; } u1, u2;
            int rowg = 16 * t + m;
            #pragma unroll
            for (int j = 0; j < 8; ++j) {
                int k = 8 * quad + j;
                u1.s[j] = bfr(Whh[rowg * 32 + k]);
                float a2v = 0.f;
                if (k == 0) a2v = Wih[rowg * 2];
                else if (k == 1) a2v = Wih[rowg * 2 + 1];
                else if (k == 2) a2v = (rowg < 64) ? (bih[rowg] + bhh[rowg]) : bih[rowg];
                u2.s[j] = bfr(a2v);
            }
            A1[t] = u1.v; A2[t] = u2.v;
        }
        {
            union { short s[8]; short8 v; } u3;
            #pragma unroll
            for (int j = 0; j < 8; ++j) {
                int k = 8 * quad + j;
                float v = (m == 0) ? Wv[k] : (m == 1) ? Wsc[k] : 0.f;
                u3.s[j] = bfr(v);
            }
            A3 = u3.v;
        }
        #pragma unroll
        for (int t = 0; t < 6; ++t) { KEEPA(A1[t]); KEEPA(A2[t]); }
        KEEPA(A3);

        float bn0[4], bn1[4];
        #pragma unroll
        for (int e = 0; e < 4; ++e) {
            int r0 = quad * 4 + e;
            bn0[e] = bhh[64 + r0];  bn1[e] = bhh[80 + r0];
        }
        const float bv0 = bv[0], bs0 = bs[0];

        // ---- staging: entry j of chain n = chunk-local spike baseL + n*8 - 9 + j ----
        for (int e = lane; e < CHAINS * EPC; e += 64) {
            int n = e / EPC, j = e - n * EPC;
            int l = baseL + n * SEG - (WARM + 1) + j;
            int cc = c, ll = l;
            while (ll < 0 && cc > lo) { --cc; ll += cnt[cc]; }
            if (ll < 0) ll = 0;                 // global-start clamp (spike 0, t=0)
            int cm = cnt[cc];
            if (ll >= cm) ll = cm - 1;          // tail clamp: feeds only guarded-inactive outputs
            int t = spk[cc * 1024 + ll];
            st[e] = make_float2((float)t, x[t]);
        }
        __builtin_amdgcn_wave_barrier();

        float h0[4], h1[4];
        #pragma unroll
        for (int e = 0; e < 4; ++e) { h0[e] = 0.f; h1[e] = 0.f; }
        short8 B1 = (short8)0;
        float tprev = st[m * EPC].x;

        for (int j = 0; j < SEG + WARM; ++j) {
            float2 cur = st[m * EPC + j + 1];   // 4 lanes/chain same addr: broadcast
            float xt = cur.y;
            float d = (cur.x - tprev) * 0.0078125f;
            tprev = cur.x;

            unsigned p0 = (__float_as_uint(d) & 0xFFFF0000u) | (__float_as_uint(xt) >> 16);
            unsigned p1 = 0x00003F80u;
            p0 = (quad == 0) ? p0 : 0u;
            p1 = (quad == 0) ? p1 : 0u;
            union { unsigned u[4]; short8 v; } b2u;
            b2u.u[0] = p0; b2u.u[1] = p1; b2u.u[2] = 0u; b2u.u[3] = 0u;
            short8 B2 = b2u.v;

            f4 z4 = {0.f, 0.f, 0.f, 0.f};
            f4 Drz[4], Dh0, Dh1, Di0, Di1;
            f4 tmp0 = __builtin_amdgcn_mfma_f32_16x16x32_bf16(A2[0], B2, z4, 0, 0, 0);
            f4 tmp1 = __builtin_amdgcn_mfma_f32_16x16x32_bf16(A2[1], B2, z4, 0, 0, 0);
            f4 tmp2 = __builtin_amdgcn_mfma_f32_16x16x32_bf16(A2[2], B2, z4, 0, 0, 0);
            f4 tmp3 = __builtin_amdgcn_mfma_f32_16x16x32_bf16(A2[3], B2, z4, 0, 0, 0);
            Di0 = __builtin_amdgcn_mfma_f32_16x16x32_bf16(A2[4], B2, z4, 0, 0, 0);
            Di1 = __builtin_amdgcn_mfma_f32_16x16x32_bf16(A2[5], B2, z4, 0, 0, 0);
            Drz[0] = __builtin_amdgcn_mfma_f32_16x16x32_bf16(A1[0], B1, tmp0, 0, 0, 0);
            Drz[1] = __builtin_amdgcn_mfma_f32_16x16x32_bf16(A1[1], B1, tmp1, 0, 0, 0);
            Drz[2] = __builtin_amdgcn_mfma_f32_16x16x32_bf16(A1[2], B1, tmp2, 0, 0, 0);
            Drz[3] = __builtin_amdgcn_mfma_f32_16x16x32_bf16(A1[3], B1, tmp3, 0, 0, 0);
            Dh0 = __builtin_amdgcn_mfma_f32_16x16x32_bf16(A1[4], B1, z4, 0, 0, 0);
            Dh1 = __builtin_amdgcn_mfma_f32_16x16x32_bf16(A1[5], B1, z4, 0, 0, 0);

            #pragma unroll
            for (int e = 0; e < 4; ++e) {
                float r0 = __builtin_amdgcn_rcpf(1.f + __builtin_amdgcn_exp2f(-1.44269504089f * Drz[0][e]));
                float r1 = __builtin_amdgcn_rcpf(1.f + __builtin_amdgcn_exp2f(-1.44269504089f * Drz[1][e]));
                float zz0 = __builtin_amdgcn_rcpf(1.f + __builtin_amdgcn_exp2f(-1.44269504089f * Drz[2][e]));
                float zz1 = __builtin_amdgcn_rcpf(1.f + __builtin_amdgcn_exp2f(-1.44269504089f * Drz[3][e]));
                float np0 = fmaf(r0, Dh0[e] + bn0[e], Di0[e]);
                float np1 = fmaf(r1, Dh1[e] + bn1[e], Di1[e]);
                float en0 = __builtin_amdgcn_exp2f(2.88539008178f * np0);
                float en1 = __builtin_amdgcn_exp2f(2.88539008178f * np1);
                float n0 = fmaf(-2.f, __builtin_amdgcn_rcpf(1.f + en0), 1.f);
                float n1 = fmaf(-2.f, __builtin_amdgcn_rcpf(1.f + en1), 1.f);
                h0[e] = fmaf(zz0, h0[e] - n0, n0);
                h1[e] = fmaf(zz1, h1[e] - n1, n1);
            }

            unsigned q0 = (__float_as_uint(h0[1]) & 0xFFFF0000u) | (__float_as_uint(h0[0]) >> 16);
            unsigned q1 = (__float_as_uint(h0[3]) & 0xFFFF0000u) | (__float_as_uint(h0[2]) >> 16);
            unsigned q2 = (__float_as_uint(h1[1]) & 0xFFFF0000u) | (__float_as_uint(h1[0]) >> 16);
            unsigned q3 = (__float_as_uint(h1[3]) & 0xFFFF0000u) | (__float_as_uint(h1[2]) >> 16);
            *(uint2*)&hx[m * 20 + 2 * quad]     = make_uint2(q0, q1);
            *(uint2*)&hx[m * 20 + 8 + 2 * quad] = make_uint2(q2, q3);
            __builtin_amdgcn_wave_barrier();
            union { uint4 u; short8 v; } bu;
            bu.u = *(const uint4*)&hx[m * 20 + 4 * quad];
            B1 = bu.v;

            if (j >= WARM) {
                f4 Dab = __builtin_amdgcn_mfma_f32_16x16x32_bf16(A3, B1, z4, 0, 0, 0);
                if (quad == 0) {
                    int lsg = baseL + m * SEG + (j - WARM);
                    if (lsg < cntc)
                        *(float2*)&ab[2 * (m * SEG + j - WARM)] =
                            make_float2(Dab[0] + bv0, Dab[1] + bs0);
                }
            }
        }
        __builtin_amdgcn_wave_barrier();

        // ---- expansion: local spike sl0 fills out[t] for t in [t_s, t_next) ----
        #pragma unroll
        for (int h = 0; h < 2; ++h) {
            int sl = lane + 64 * h;               // sub-group-local spike 0..127
            int sl0 = baseL + sl;
            if (sl0 < cntc) {
                int n = sl >> 3, jj = sl & 7;
                float ts = st[n * EPC + (WARM + 1) + jj].x;
                int tnext;
                if (sl0 + 1 >= cntc) tnext = (b == NCH) ? T_LEN : s_fs;
                else if (sl + 1 < GSP) {
                    int n2 = (sl + 1) >> 3, j2 = (sl + 1) & 7;
                    tnext = (int)st[n2 * EPC + (WARM + 1) + j2].x;
                } else tnext = spk[c * 1024 + sl0 + 1];
                float2 abv = *(const float2*)&ab[2 * sl];
                int tsi = (int)ts;
                for (int t = tsi; t < tnext; ++t)
                    out[t] = fmaf(abv.y, (float)(t - tsi) * 0.0078125f, abv.x);
            }
        }
    }

    // ---- N total (tail work, one block, off the critical path) ----
    if (b == NCH && tid < 64) {
        for (int k = 0; k < 8; ++k) waitflag(flags, lane * 8 + k);
        __threadfence();
        int s = 0;
        for (int k = 0; k < 8; ++k) s += cnt[lane * 8 + k];
        for (int d = 32; d; d >>= 1) s += __shfl_down(s, d, 64);
        if (lane == 0 && T_LEN < out_size) out[T_LEN] = (float)s;
    }
}

extern "C" void kernel_launch(void* const* d_in, const int* in_sizes, int n_in,
                              void* d_out, int out_size, void* d_ws, size_t ws_size,
                              hipStream_t stream)
{
    const float* x   = (const float*)d_in[0];
    const float* Wih = (const float*)d_in[1];
    const float* Whh = (const float*)d_in[2];
    const float* bih = (const float*)d_in[3];
    const float* bhh = (const float*)d_in[4];
    const float* Wv  = (const float*)d_in[5];
    const float* bv  = (const float*)d_in[6];
    const float* Wsc = (const float*)d_in[7];
    const float* bs  = (const float*)d_in[8];
    float* out = (float*)d_out;

    char* ws = (char*)d_ws;
    int* cnt   = (int*)(ws + OFF_CNT);
    int* flags = (int*)(ws + OFF_FLAG);
    int* spk   = (int*)(ws + OFF_SPK);

    k_all<<<NCH + 1, 256, 0, stream>>>(x, Wih, Whh, bih, bhh, Wv, bv, Wsc, bs,
                                       out, out_size, cnt, spk, flags);
}

// Round 9
// 131.632 us; speedup vs baseline: 1.0067x; 1.0067x over previous
//
#include <hip/hip_runtime.h>
#include <stdint.h>

#define T_LEN 524288
#define SEG 8
#define WARM 8
#define EPC (SEG + WARM + 1)   // 17 staged (t,x) entries per chain
#define CHAINS 16
#define GSP (CHAINS * SEG)     // 128 spikes per wave sub-group
#define NCH 512                // chunks (1024 t each)

typedef short short8 __attribute__((ext_vector_type(8)));
typedef float f4 __attribute__((ext_vector_type(4)));
#define KEEPA(v) asm volatile("" : "+v"(v))

// ---- workspace layout (bytes) ----
static const size_t OFF_CNT  = 0;          // 512 int
static const size_t OFF_FLAG = 4096;       // 1024 int (pairs)
static const size_t OFF_SPK  = 16384;      // 512*1024 int (chunk-local spike times)

__device__ __forceinline__ short bfr(float f) {        // fp32 -> bf16 RNE
    uint32_t u = __float_as_uint(f);
    u = (u + 0x7fffu + ((u >> 16) & 1u)) >> 16;
    return (short)u;
}

// padded LDS index: +1 word per 32 -> lane-stride-4 accesses are 2 lanes/bank (free)
#define IDX(j) ((j) + ((j) >> 5))

// poison-proof flag pair: f2 = ~f1, a single fill constant can never match both
__device__ __forceinline__ int flagval(int c, int which) {
    int v = 0x51AB7E3D ^ (int)((unsigned)c * 2654435761u);
    return which ? ~v : v;
}
__device__ __forceinline__ void waitflag(int* flags, int c) {
    const int e1 = flagval(c, 0), e2 = flagval(c, 1);
    while (__hip_atomic_load(&flags[2 * c],     __ATOMIC_RELAXED, __HIP_MEMORY_SCOPE_AGENT) != e1 ||
           __hip_atomic_load(&flags[2 * c + 1], __ATOMIC_RELAXED, __HIP_MEMORY_SCOPE_AGENT) != e2)
        __builtin_amdgcn_s_sleep(2);
}

struct MaskSM  { float tile[1190]; float cs2[1190]; float wsum[4]; int wtot[4]; };
struct ChainSM { float2 st[4][CHAINS * EPC]; unsigned hx[4][CHAINS * 20]; float ab[4][2 * GSP]; };
union  SMU     { MaskSM m; ChainSM c; };

// ---- single fused kernel: block b masks chunk b, chains chunk b-1 ----
// Cross-block deps point strictly BACKWARD (flags b-5..b-1) -> deadlock-free
// under in-order dispatch at any residency (no co-residency assumption).
// waves_per_eu(2): allow up to ~256 VGPR so the 13 MFMA fragments stay
// resident (R8's VGPR=68 spilled them -> 70us; same fix as proven k_chain).
__global__ __attribute__((amdgpu_waves_per_eu(2)))
__launch_bounds__(256)
void k_all(const float* __restrict__ x,  const float* __restrict__ Wih,
           const float* __restrict__ Whh, const float* __restrict__ bih,
           const float* __restrict__ bhh, const float* __restrict__ Wv,
           const float* __restrict__ bv,  const float* __restrict__ Wsc,
           const float* __restrict__ bs,  float* __restrict__ out, int out_size,
           int* __restrict__ cnt, int* __restrict__ spk, int* __restrict__ flags)
{
    __shared__ SMU sm;
    __shared__ int s_fs;                    // first spike time of OWN chunk b
    const int b = blockIdx.x;
    const int tid = threadIdx.x;
    const int lane = tid & 63, w4 = tid >> 6;

    if (tid == 0) s_fs = T_LEN;

    // ================= phase A: mask + local scatter for chunk b =================
    if (b < NCH) {
        const int bs_ = b * 1024;
        for (int j = tid; j < 1154; j += 256) {
            int g = bs_ - 130 + j;
            sm.m.tile[IDX(j)] = (g >= 0) ? x[g] : 0.f;
        }
        __syncthreads();

        const int j0 = tid * 5;
        float p[5]; float run = 0.f;
        #pragma unroll
        for (int k = 0; k < 5; ++k) {
            float v = (j0 + k < 1154) ? sm.m.tile[IDX(j0 + k)] : 0.f;
            run = fmaf(v, v, run);
            p[k] = run;
        }
        float incl = run;
        for (int d = 1; d < 64; d <<= 1) {
            float u = __shfl_up(incl, d, 64);
            if (lane >= d) incl += u;
        }
        if (lane == 63) sm.m.wsum[w4] = incl;
        __syncthreads();
        float base = incl - run;
        for (int i = 0; i < w4; ++i) base += sm.m.wsum[i];
        #pragma unroll
        for (int k = 0; k < 5; ++k)
            if (j0 + k < 1154) sm.m.cs2[IDX(j0 + k)] = base + p[k];
        __syncthreads();

        const int loc = tid * 4;
        float tv[6];
        #pragma unroll
        for (int q = 0; q < 6; ++q) tv[q] = sm.m.tile[IDX(loc + 128 + q)];
        float4 mf; int mbit[4]; int msum = 0;
        float* fp = &mf.x;
        #pragma unroll
        for (int it = 0; it < 4; ++it) {
            int t = bs_ + loc + it;
            int cdiv = t < 128 ? (t < 1 ? 1 : t) : 128;
            float s = sm.m.cs2[IDX(loc + 129 + it)] - sm.m.cs2[IDX(loc + 1 + it)];
            float rms = sqrtf(fmaxf(s, 0.f) / (float)cdiv) + 1e-8f;
            float xt = tv[it + 2];
            float pr = 2.f * tv[it + 1] - tv[it];
            bool m = (t < 2) || (fabsf(xt - pr) > 2.5f * rms);
            mbit[it] = m ? 1 : 0; fp[it] = m ? 1.f : 0.f; msum += m ? 1 : 0;
        }
        int oi = T_LEN + 1 + bs_ + loc;
        if (oi + 3 < out_size) *(float4*)(out + oi) = mf;

        int e1 = mbit[0], e2 = mbit[0] + mbit[1], e3 = e2 + mbit[2];
        int incs = msum;
        for (int d = 1; d < 64; d <<= 1) {
            int u = __shfl_up(incs, d, 64);
            if (lane >= d) incs += u;
        }
        if (lane == 63) sm.m.wtot[w4] = incs;
        __syncthreads();
        int woff = 0;
        for (int i = 0; i < w4; ++i) woff += sm.m.wtot[i];
        int texcl = woff + incs - msum;
        int ee[4] = {0, e1, e2, e3};
        int* sp = spk + b * 1024 + texcl;
        #pragma unroll
        for (int k = 0; k < 4; ++k)
            if (mbit[k]) sp[ee[k]] = bs_ + loc + k;
        if (msum > 0 && texcl == 0) {       // exactly one thread: the first spiker
            int fk = mbit[0] ? 0 : mbit[1] ? 1 : mbit[2] ? 2 : 3;
            s_fs = bs_ + loc + fk;
        }
        if (tid == 0)
            cnt[b] = sm.m.wtot[0] + sm.m.wtot[1] + sm.m.wtot[2] + sm.m.wtot[3];
        __syncthreads();                    // all spk/cnt stores drained (vmcnt 0)
        if (tid == 0) {
            __threadfence();                // agent release (L2 writeback)
            __hip_atomic_store(&flags[2 * b],     flagval(b, 0), __ATOMIC_RELEASE, __HIP_MEMORY_SCOPE_AGENT);
            __hip_atomic_store(&flags[2 * b + 1], flagval(b, 1), __ATOMIC_RELEASE, __HIP_MEMORY_SCOPE_AGENT);
        }
    }
    if (b == 0) return;

    // ================= phase B: chains for chunk c = b-1 =================
    const int c = b - 1;
    const int lo = (c - 4 > 0) ? c - 4 : 0;
    if (tid == 0) {
        for (int cc = lo; cc <= c; ++cc) waitflag(flags, cc);
        __threadfence();                    // agent acquire (cache inv)
    }
    __syncthreads();                        // union transition + flag visibility

    const int cntc = cnt[c];
    const int baseL = 128 * w4;             // this wave's sub-group of chunk c
    const int m = lane & 15, quad = lane >> 4;

    if (baseL < cntc) {
        float2*   st = sm.c.st[w4];
        unsigned* hx = sm.c.hx[w4];
        float*    ab = sm.c.ab[w4];

        // ---- A fragments (static): A[m][k], k = 8*quad + j ----
        short8 A1[6], A2[6], A3;
        #pragma unroll
        for (int t = 0; t < 6; ++t) {
            union { short s[8]; short8 v; } u1, u2;
            int rowg = 16 * t + m;
            #pragma unroll
            for (int j = 0; j < 8; ++j) {
                int k = 8 * quad + j;
                u1.s[j] = bfr(Whh[rowg * 32 + k]);
                float a2v = 0.f;
                if (k == 0) a2v = Wih[rowg * 2];
                else if (k == 1) a2v = Wih[rowg * 2 + 1];
                else if (k == 2) a2v = (rowg < 64) ? (bih[rowg] + bhh[rowg]) : bih[rowg];
                u2.s[j] = bfr(a2v);
            }
            A1[t] = u1.v; A2[t] = u2.v;
        }
        {
            union { short s[8]; short8 v; } u3;
            #pragma unroll
            for (int j = 0; j < 8; ++j) {
                int k = 8 * quad + j;
                float v = (m == 0) ? Wv[k] : (m == 1) ? Wsc[k] : 0.f;
                u3.s[j] = bfr(v);
            }
            A3 = u3.v;
        }
        #pragma unroll
        for (int t = 0; t < 6; ++t) { KEEPA(A1[t]); KEEPA(A2[t]); }
        KEEPA(A3);

        float bn0[4], bn1[4];
        #pragma unroll
        for (int e = 0; e < 4; ++e) {
            int r0 = quad * 4 + e;
            bn0[e] = bhh[64 + r0];  bn1[e] = bhh[80 + r0];
        }
        const float bv0 = bv[0], bs0 = bs[0];

        // ---- staging: entry j of chain n = chunk-local spike baseL + n*8 - 9 + j ----
        for (int e = lane; e < CHAINS * EPC; e += 64) {
            int n = e / EPC, j = e - n * EPC;
            int l = baseL + n * SEG - (WARM + 1) + j;
            int cc = c, ll = l;
            while (ll < 0 && cc > lo) { --cc; ll += cnt[cc]; }
            if (ll < 0) ll = 0;                 // global-start clamp (spike 0, t=0)
            int cm = cnt[cc];
            if (ll >= cm) ll = cm - 1;          // tail clamp: feeds only guarded-inactive outputs
            int t = spk[cc * 1024 + ll];
            st[e] = make_float2((float)t, x[t]);
        }
        __builtin_amdgcn_wave_barrier();

        float h0[4], h1[4];
        #pragma unroll
        for (int e = 0; e < 4; ++e) { h0[e] = 0.f; h1[e] = 0.f; }
        short8 B1 = (short8)0;
        float tprev = st[m * EPC].x;

        for (int j = 0; j < SEG + WARM; ++j) {
            float2 cur = st[m * EPC + j + 1];   // 4 lanes/chain same addr: broadcast
            float xt = cur.y;
            float d = (cur.x - tprev) * 0.0078125f;
            tprev = cur.x;

            unsigned p0 = (__float_as_uint(d) & 0xFFFF0000u) | (__float_as_uint(xt) >> 16);
            unsigned p1 = 0x00003F80u;
            p0 = (quad == 0) ? p0 : 0u;
            p1 = (quad == 0) ? p1 : 0u;
            union { unsigned u[4]; short8 v; } b2u;
            b2u.u[0] = p0; b2u.u[1] = p1; b2u.u[2] = 0u; b2u.u[3] = 0u;
            short8 B2 = b2u.v;

            f4 z4 = {0.f, 0.f, 0.f, 0.f};
            f4 Drz[4], Dh0, Dh1, Di0, Di1;
            f4 tmp0 = __builtin_amdgcn_mfma_f32_16x16x32_bf16(A2[0], B2, z4, 0, 0, 0);
            f4 tmp1 = __builtin_amdgcn_mfma_f32_16x16x32_bf16(A2[1], B2, z4, 0, 0, 0);
            f4 tmp2 = __builtin_amdgcn_mfma_f32_16x16x32_bf16(A2[2], B2, z4, 0, 0, 0);
            f4 tmp3 = __builtin_amdgcn_mfma_f32_16x16x32_bf16(A2[3], B2, z4, 0, 0, 0);
            Di0 = __builtin_amdgcn_mfma_f32_16x16x32_bf16(A2[4], B2, z4, 0, 0, 0);
            Di1 = __builtin_amdgcn_mfma_f32_16x16x32_bf16(A2[5], B2, z4, 0, 0, 0);
            Drz[0] = __builtin_amdgcn_mfma_f32_16x16x32_bf16(A1[0], B1, tmp0, 0, 0, 0);
            Drz[1] = __builtin_amdgcn_mfma_f32_16x16x32_bf16(A1[1], B1, tmp1, 0, 0, 0);
            Drz[2] = __builtin_amdgcn_mfma_f32_16x16x32_bf16(A1[2], B1, tmp2, 0, 0, 0);
            Drz[3] = __builtin_amdgcn_mfma_f32_16x16x32_bf16(A1[3], B1, tmp3, 0, 0, 0);
            Dh0 = __builtin_amdgcn_mfma_f32_16x16x32_bf16(A1[4], B1, z4, 0, 0, 0);
            Dh1 = __builtin_amdgcn_mfma_f32_16x16x32_bf16(A1[5], B1, z4, 0, 0, 0);

            #pragma unroll
            for (int e = 0; e < 4; ++e) {
                float r0 = __builtin_amdgcn_rcpf(1.f + __builtin_amdgcn_exp2f(-1.44269504089f * Drz[0][e]));
                float r1 = __builtin_amdgcn_rcpf(1.f + __builtin_amdgcn_exp2f(-1.44269504089f * Drz[1][e]));
                float zz0 = __builtin_amdgcn_rcpf(1.f + __builtin_amdgcn_exp2f(-1.44269504089f * Drz[2][e]));
                float zz1 = __builtin_amdgcn_rcpf(1.f + __builtin_amdgcn_exp2f(-1.44269504089f * Drz[3][e]));
                float np0 = fmaf(r0, Dh0[e] + bn0[e], Di0[e]);
                float np1 = fmaf(r1, Dh1[e] + bn1[e], Di1[e]);
                float en0 = __builtin_amdgcn_exp2f(2.88539008178f * np0);
                float en1 = __builtin_amdgcn_exp2f(2.88539008178f * np1);
                float n0 = fmaf(-2.f, __builtin_amdgcn_rcpf(1.f + en0), 1.f);
                float n1 = fmaf(-2.f, __builtin_amdgcn_rcpf(1.f + en1), 1.f);
                h0[e] = fmaf(zz0, h0[e] - n0, n0);
                h1[e] = fmaf(zz1, h1[e] - n1, n1);
            }

            unsigned q0 = (__float_as_uint(h0[1]) & 0xFFFF0000u) | (__float_as_uint(h0[0]) >> 16);
            unsigned q1 = (__float_as_uint(h0[3]) & 0xFFFF0000u) | (__float_as_uint(h0[2]) >> 16);
            unsigned q2 = (__float_as_uint(h1[1]) & 0xFFFF0000u) | (__float_as_uint(h1[0]) >> 16);
            unsigned q3 = (__float_as_uint(h1[3]) & 0xFFFF0000u) | (__float_as_uint(h1[2]) >> 16);
            *(uint2*)&hx[m * 20 + 2 * quad]     = make_uint2(q0, q1);
            *(uint2*)&hx[m * 20 + 8 + 2 * quad] = make_uint2(q2, q3);
            __builtin_amdgcn_wave_barrier();
            union { uint4 u; short8 v; } bu;
            bu.u = *(const uint4*)&hx[m * 20 + 4 * quad];
            B1 = bu.v;

            if (j >= WARM) {
                f4 Dab = __builtin_amdgcn_mfma_f32_16x16x32_bf16(A3, B1, z4, 0, 0, 0);
                if (quad == 0) {
                    int lsg = baseL + m * SEG + (j - WARM);
                    if (lsg < cntc)
                        *(float2*)&ab[2 * (m * SEG + j - WARM)] =
                            make_float2(Dab[0] + bv0, Dab[1] + bs0);
                }
            }
        }
        __builtin_amdgcn_wave_barrier();

        // ---- expansion: local spike sl0 fills out[t] for t in [t_s, t_next) ----
        #pragma unroll
        for (int h = 0; h < 2; ++h) {
            int sl = lane + 64 * h;               // sub-group-local spike 0..127
            int sl0 = baseL + sl;
            if (sl0 < cntc) {
                int n = sl >> 3, jj = sl & 7;
                float ts = st[n * EPC + (WARM + 1) + jj].x;
                int tnext;
                if (sl0 + 1 >= cntc) tnext = (b == NCH) ? T_LEN : s_fs;
                else if (sl + 1 < GSP) {
                    int n2 = (sl + 1) >> 3, j2 = (sl + 1) & 7;
                    tnext = (int)st[n2 * EPC + (WARM + 1) + j2].x;
                } else tnext = spk[c * 1024 + sl0 + 1];
                float2 abv = *(const float2*)&ab[2 * sl];
                int tsi = (int)ts;
                for (int t = tsi; t < tnext; ++t)
                    out[t] = fmaf(abv.y, (float)(t - tsi) * 0.0078125f, abv.x);
            }
        }
    }

    // ---- N total (tail work, one block, off the critical path) ----
    if (b == NCH && tid < 64) {
        for (int k = 0; k < 8; ++k) waitflag(flags, lane * 8 + k);
        __threadfence();
        int s = 0;
        for (int k = 0; k < 8; ++k) s += cnt[lane * 8 + k];
        for (int d = 32; d; d >>= 1) s += __shfl_down(s, d, 64);
        if (lane == 0 && T_LEN < out_size) out[T_LEN] = (float)s;
    }
}

extern "C" void kernel_launch(void* const* d_in, const int* in_sizes, int n_in,
                              void* d_out, int out_size, void* d_ws, size_t ws_size,
                              hipStream_t stream)
{
    const float* x   = (const float*)d_in[0];
    const float* Wih = (const float*)d_in[1];
    const float* Whh = (const float*)d_in[2];
    const float* bih = (const float*)d_in[3];
    const float* bhh = (const float*)d_in[4];
    const float* Wv  = (const float*)d_in[5];
    const float* bv  = (const float*)d_in[6];
    const float* Wsc = (const float*)d_in[7];
    const float* bs  = (const float*)d_in[8];
    float* out = (float*)d_out;

    char* ws = (char*)d_ws;
    int* cnt   = (int*)(ws + OFF_CNT);
    int* flags = (int*)(ws + OFF_FLAG);
    int* spk   = (int*)(ws + OFF_SPK);

    k_all<<<NCH + 1, 256, 0, stream>>>(x, Wih, Whh, bih, bhh, Wv, bv, Wsc, bs,
                                       out, out_size, cnt, spk, flags);
}

// Round 10
// 101.971 us; speedup vs baseline: 1.2995x; 1.2909x over previous
//
#include <hip/hip_runtime.h>
#include <stdint.h>

#define T_LEN 524288
#define SEG 8
#define WARM 8
#define EPC (SEG + WARM + 1)   // 17 staged (t,x) entries per chain
#define CHAINS 16
#define GSP (CHAINS * SEG)     // 128 spikes per wave sub-group
#define NCH 512                // chunks (1024 t each)

typedef short short8 __attribute__((ext_vector_type(8)));
typedef float f4 __attribute__((ext_vector_type(4)));
#define KEEPA(v) asm volatile("" : "+v"(v))

// ---- workspace layout (bytes) ----
static const size_t OFF_FLAG = 4096;       // 1024 int (pairs, cnt embedded)
static const size_t OFF_SPK  = 16384;      // 512*1024 int (chunk-local spike times)

__device__ __forceinline__ short bfr(float f) {        // fp32 -> bf16 RNE
    uint32_t u = __float_as_uint(f);
    u = (u + 0x7fffu + ((u >> 16) & 1u)) >> 16;
    return (short)u;
}

// padded LDS index: +1 word per 32 -> lane-stride-4 accesses are 2 lanes/bank (free)
#define IDX(j) ((j) + ((j) >> 5))

// ---- coherent handoff (no fences, no L2 wb/inv):
// flag pair carries cnt in low 11 bits; f2 = ~f1 (poison fill v,v can never match).
__device__ __forceinline__ unsigned flaghi(int c) {
    return (0x51AB7E3Du ^ ((unsigned)c * 2654435761u)) & ~0x7FFu;
}
__device__ __forceinline__ int wait_cnt(int* flags, int c) {
    const unsigned hi = flaghi(c);
    for (;;) {
        int f1 = __hip_atomic_load(&flags[2 * c],     __ATOMIC_RELAXED, __HIP_MEMORY_SCOPE_AGENT);
        int f2 = __hip_atomic_load(&flags[2 * c + 1], __ATOMIC_RELAXED, __HIP_MEMORY_SCOPE_AGENT);
        if (((unsigned)f1 & ~0x7FFu) == hi && f2 == ~f1) return f1 & 0x7FF;
        __builtin_amdgcn_s_sleep(2);
    }
}
__device__ __forceinline__ int spk_ld(const int* spk, int idx) {
    return __hip_atomic_load((int*)&spk[idx], __ATOMIC_RELAXED, __HIP_MEMORY_SCOPE_AGENT);
}

struct MaskSM  { float tile[1190]; float cs2[1190]; float wsum[4]; int wtot[4]; };
struct ChainSM { float2 st[4][CHAINS * EPC]; unsigned hx[4][CHAINS * 20]; float ab[4][2 * GSP]; };
union  SMU     { MaskSM m; ChainSM c; };

// ---- single fused kernel: block b masks chunk b, chains chunk b-1 ----
// Cross-block deps point strictly BACKWARD (flags b-5..b-1) -> deadlock-free
// under in-order dispatch at any residency. All cross-block data (spk, cnt)
// moves through agent-scope relaxed atomics => NO threadfence, NO L2 wb/inv
// (R8/R9's 67us was the consumer-side buffer_inv storm trashing L2).
__global__ __attribute__((amdgpu_waves_per_eu(2)))
__launch_bounds__(256)
void k_all(const float* __restrict__ x,  const float* __restrict__ Wih,
           const float* __restrict__ Whh, const float* __restrict__ bih,
           const float* __restrict__ bhh, const float* __restrict__ Wv,
           const float* __restrict__ bv,  const float* __restrict__ Wsc,
           const float* __restrict__ bs,  float* __restrict__ out, int out_size,
           int* __restrict__ spk, int* __restrict__ flags)
{
    __shared__ SMU sm;
    __shared__ int s_fs;                    // first spike time of OWN chunk b
    __shared__ int cnt_sh[5];               // decoded cnts for chunks lo..c
    const int b = blockIdx.x;
    const int tid = threadIdx.x;
    const int lane = tid & 63, w4 = tid >> 6;

    if (tid == 0) s_fs = T_LEN;
    int cntb = 0;                           // own-chunk count (tid0 only)

    // ================= phase A: mask + local scatter for chunk b =================
    if (b < NCH) {
        const int bs_ = b * 1024;
        for (int j = tid; j < 1154; j += 256) {
            int g = bs_ - 130 + j;
            sm.m.tile[IDX(j)] = (g >= 0) ? x[g] : 0.f;
        }
        __syncthreads();

        const int j0 = tid * 5;
        float p[5]; float run = 0.f;
        #pragma unroll
        for (int k = 0; k < 5; ++k) {
            float v = (j0 + k < 1154) ? sm.m.tile[IDX(j0 + k)] : 0.f;
            run = fmaf(v, v, run);
            p[k] = run;
        }
        float incl = run;
        for (int d = 1; d < 64; d <<= 1) {
            float u = __shfl_up(incl, d, 64);
            if (lane >= d) incl += u;
        }
        if (lane == 63) sm.m.wsum[w4] = incl;
        __syncthreads();
        float base = incl - run;
        for (int i = 0; i < w4; ++i) base += sm.m.wsum[i];
        #pragma unroll
        for (int k = 0; k < 5; ++k)
            if (j0 + k < 1154) sm.m.cs2[IDX(j0 + k)] = base + p[k];
        __syncthreads();

        const int loc = tid * 4;
        float tv[6];
        #pragma unroll
        for (int q = 0; q < 6; ++q) tv[q] = sm.m.tile[IDX(loc + 128 + q)];
        float4 mf; int mbit[4]; int msum = 0;
        float* fp = &mf.x;
        #pragma unroll
        for (int it = 0; it < 4; ++it) {
            int t = bs_ + loc + it;
            int cdiv = t < 128 ? (t < 1 ? 1 : t) : 128;
            float s = sm.m.cs2[IDX(loc + 129 + it)] - sm.m.cs2[IDX(loc + 1 + it)];
            float rms = sqrtf(fmaxf(s, 0.f) / (float)cdiv) + 1e-8f;
            float xt = tv[it + 2];
            float pr = 2.f * tv[it + 1] - tv[it];
            bool m = (t < 2) || (fabsf(xt - pr) > 2.5f * rms);
            mbit[it] = m ? 1 : 0; fp[it] = m ? 1.f : 0.f; msum += m ? 1 : 0;
        }
        int oi = T_LEN + 1 + bs_ + loc;
        if (oi + 3 < out_size) *(float4*)(out + oi) = mf;

        int e1 = mbit[0], e2 = mbit[0] + mbit[1], e3 = e2 + mbit[2];
        int incs = msum;
        for (int d = 1; d < 64; d <<= 1) {
            int u = __shfl_up(incs, d, 64);
            if (lane >= d) incs += u;
        }
        if (lane == 63) sm.m.wtot[w4] = incs;
        __syncthreads();
        int woff = 0;
        for (int i = 0; i < w4; ++i) woff += sm.m.wtot[i];
        int texcl = woff + incs - msum;
        int ee[4] = {0, e1, e2, e3};
        int sbase = b * 1024 + texcl;
        #pragma unroll
        for (int k = 0; k < 4; ++k)
            if (mbit[k])
                __hip_atomic_store(&spk[sbase + ee[k]], bs_ + loc + k,
                                   __ATOMIC_RELAXED, __HIP_MEMORY_SCOPE_AGENT);
        if (msum > 0 && texcl == 0) {       // exactly one thread: the first spiker
            int fk = mbit[0] ? 0 : mbit[1] ? 1 : mbit[2] ? 2 : 3;
            s_fs = bs_ + loc + fk;
        }
        if (tid == 0)
            cntb = sm.m.wtot[0] + sm.m.wtot[1] + sm.m.wtot[2] + sm.m.wtot[3];
        __syncthreads();                    // drains vmcnt(0): all spk stores at coherence pt
        if (tid == 0) {
            int f1 = (int)(flaghi(b) | (unsigned)cntb);
            __hip_atomic_store(&flags[2 * b],     f1,  __ATOMIC_RELAXED, __HIP_MEMORY_SCOPE_AGENT);
            __hip_atomic_store(&flags[2 * b + 1], ~f1, __ATOMIC_RELAXED, __HIP_MEMORY_SCOPE_AGENT);
        }
    }
    if (b == 0) return;

    // ================= phase B: chains for chunk c = b-1 =================
    const int c = b - 1;
    const int lo = (c - 4 > 0) ? c - 4 : 0;
    if (tid == 0)
        for (int cc = lo; cc <= c; ++cc) cnt_sh[cc - lo] = wait_cnt(flags, cc);
    __syncthreads();                        // union transition + cnt_sh visibility

    const int cntc = cnt_sh[c - lo];
    const int baseL = 128 * w4;             // this wave's sub-group of chunk c
    const int m = lane & 15, quad = lane >> 4;

    if (b <= NCH && baseL < cntc) {
        float2*   st = sm.c.st[w4];
        unsigned* hx = sm.c.hx[w4];
        float*    ab = sm.c.ab[w4];

        // ---- A fragments (static): A[m][k], k = 8*quad + j ----
        short8 A1[6], A2[6], A3;
        #pragma unroll
        for (int t = 0; t < 6; ++t) {
            union { short s[8]; short8 v; } u1, u2;
            int rowg = 16 * t + m;
            #pragma unroll
            for (int j = 0; j < 8; ++j) {
                int k = 8 * quad + j;
                u1.s[j] = bfr(Whh[rowg * 32 + k]);
                float a2v = 0.f;
                if (k == 0) a2v = Wih[rowg * 2];
                else if (k == 1) a2v = Wih[rowg * 2 + 1];
                else if (k == 2) a2v = (rowg < 64) ? (bih[rowg] + bhh[rowg]) : bih[rowg];
                u2.s[j] = bfr(a2v);
            }
            A1[t] = u1.v; A2[t] = u2.v;
        }
        {
            union { short s[8]; short8 v; } u3;
            #pragma unroll
            for (int j = 0; j < 8; ++j) {
                int k = 8 * quad + j;
                float v = (m == 0) ? Wv[k] : (m == 1) ? Wsc[k] : 0.f;
                u3.s[j] = bfr(v);
            }
            A3 = u3.v;
        }
        #pragma unroll
        for (int t = 0; t < 6; ++t) { KEEPA(A1[t]); KEEPA(A2[t]); }
        KEEPA(A3);

        float bn0[4], bn1[4];
        #pragma unroll
        for (int e = 0; e < 4; ++e) {
            int r0 = quad * 4 + e;
            bn0[e] = bhh[64 + r0];  bn1[e] = bhh[80 + r0];
        }
        const float bv0 = bv[0], bs0 = bs[0];

        // ---- staging: entry j of chain n = chunk-local spike baseL + n*8 - 9 + j ----
        for (int e = lane; e < CHAINS * EPC; e += 64) {
            int n = e / EPC, j = e - n * EPC;
            int l = baseL + n * SEG - (WARM + 1) + j;
            int cc = c, ll = l;
            while (ll < 0 && cc > lo) { --cc; ll += cnt_sh[cc - lo]; }
            if (ll < 0) ll = 0;                 // global-start clamp (spike 0, t=0)
            int cm = cnt_sh[cc - lo];
            if (ll >= cm) ll = cm - 1;          // tail clamp: feeds only guarded-inactive outputs
            int t = spk_ld(spk, cc * 1024 + ll);
            st[e] = make_float2((float)t, x[t]);
        }
        __builtin_amdgcn_wave_barrier();

        float h0[4], h1[4];
        #pragma unroll
        for (int e = 0; e < 4; ++e) { h0[e] = 0.f; h1[e] = 0.f; }
        short8 B1 = (short8)0;
        float tprev = st[m * EPC].x;

        for (int j = 0; j < SEG + WARM; ++j) {
            float2 cur = st[m * EPC + j + 1];   // 4 lanes/chain same addr: broadcast
            float xt = cur.y;
            float d = (cur.x - tprev) * 0.0078125f;
            tprev = cur.x;

            unsigned p0 = (__float_as_uint(d) & 0xFFFF0000u) | (__float_as_uint(xt) >> 16);
            unsigned p1 = 0x00003F80u;
            p0 = (quad == 0) ? p0 : 0u;
            p1 = (quad == 0) ? p1 : 0u;
            union { unsigned u[4]; short8 v; } b2u;
            b2u.u[0] = p0; b2u.u[1] = p1; b2u.u[2] = 0u; b2u.u[3] = 0u;
            short8 B2 = b2u.v;

            f4 z4 = {0.f, 0.f, 0.f, 0.f};
            f4 Drz[4], Dh0, Dh1, Di0, Di1;
            f4 tmp0 = __builtin_amdgcn_mfma_f32_16x16x32_bf16(A2[0], B2, z4, 0, 0, 0);
            f4 tmp1 = __builtin_amdgcn_mfma_f32_16x16x32_bf16(A2[1], B2, z4, 0, 0, 0);
            f4 tmp2 = __builtin_amdgcn_mfma_f32_16x16x32_bf16(A2[2], B2, z4, 0, 0, 0);
            f4 tmp3 = __builtin_amdgcn_mfma_f32_16x16x32_bf16(A2[3], B2, z4, 0, 0, 0);
            Di0 = __builtin_amdgcn_mfma_f32_16x16x32_bf16(A2[4], B2, z4, 0, 0, 0);
            Di1 = __builtin_amdgcn_mfma_f32_16x16x32_bf16(A2[5], B2, z4, 0, 0, 0);
            Drz[0] = __builtin_amdgcn_mfma_f32_16x16x32_bf16(A1[0], B1, tmp0, 0, 0, 0);
            Drz[1] = __builtin_amdgcn_mfma_f32_16x16x32_bf16(A1[1], B1, tmp1, 0, 0, 0);
            Drz[2] = __builtin_amdgcn_mfma_f32_16x16x32_bf16(A1[2], B1, tmp2, 0, 0, 0);
            Drz[3] = __builtin_amdgcn_mfma_f32_16x16x32_bf16(A1[3], B1, tmp3, 0, 0, 0);
            Dh0 = __builtin_amdgcn_mfma_f32_16x16x32_bf16(A1[4], B1, z4, 0, 0, 0);
            Dh1 = __builtin_amdgcn_mfma_f32_16x16x32_bf16(A1[5], B1, z4, 0, 0, 0);

            #pragma unroll
            for (int e = 0; e < 4; ++e) {
                float r0 = __builtin_amdgcn_rcpf(1.f + __builtin_amdgcn_exp2f(-1.44269504089f * Drz[0][e]));
                float r1 = __builtin_amdgcn_rcpf(1.f + __builtin_amdgcn_exp2f(-1.44269504089f * Drz[1][e]));
                float zz0 = __builtin_amdgcn_rcpf(1.f + __builtin_amdgcn_exp2f(-1.44269504089f * Drz[2][e]));
                float zz1 = __builtin_amdgcn_rcpf(1.f + __builtin_amdgcn_exp2f(-1.44269504089f * Drz[3][e]));
                float np0 = fmaf(r0, Dh0[e] + bn0[e], Di0[e]);
                float np1 = fmaf(r1, Dh1[e] + bn1[e], Di1[e]);
                float en0 = __builtin_amdgcn_exp2f(2.88539008178f * np0);
                float en1 = __builtin_amdgcn_exp2f(2.88539008178f * np1);
                float n0 = fmaf(-2.f, __builtin_amdgcn_rcpf(1.f + en0), 1.f);
                float n1 = fmaf(-2.f, __builtin_amdgcn_rcpf(1.f + en1), 1.f);
                h0[e] = fmaf(zz0, h0[e] - n0, n0);
                h1[e] = fmaf(zz1, h1[e] - n1, n1);
            }

            unsigned q0 = (__float_as_uint(h0[1]) & 0xFFFF0000u) | (__float_as_uint(h0[0]) >> 16);
            unsigned q1 = (__float_as_uint(h0[3]) & 0xFFFF0000u) | (__float_as_uint(h0[2]) >> 16);
            unsigned q2 = (__float_as_uint(h1[1]) & 0xFFFF0000u) | (__float_as_uint(h1[0]) >> 16);
            unsigned q3 = (__float_as_uint(h1[3]) & 0xFFFF0000u) | (__float_as_uint(h1[2]) >> 16);
            *(uint2*)&hx[m * 20 + 2 * quad]     = make_uint2(q0, q1);
            *(uint2*)&hx[m * 20 + 8 + 2 * quad] = make_uint2(q2, q3);
            __builtin_amdgcn_wave_barrier();
            union { uint4 u; short8 v; } bu;
            bu.u = *(const uint4*)&hx[m * 20 + 4 * quad];
            B1 = bu.v;

            if (j >= WARM) {
                f4 Dab = __builtin_amdgcn_mfma_f32_16x16x32_bf16(A3, B1, z4, 0, 0, 0);
                if (quad == 0) {
                    int lsg = baseL + m * SEG + (j - WARM);
                    if (lsg < cntc)
                        *(float2*)&ab[2 * (m * SEG + j - WARM)] =
                            make_float2(Dab[0] + bv0, Dab[1] + bs0);
                }
            }
        }
        __builtin_amdgcn_wave_barrier();

        // ---- expansion: local spike sl0 fills out[t] for t in [t_s, t_next) ----
        #pragma unroll
        for (int h = 0; h < 2; ++h) {
            int sl = lane + 64 * h;               // sub-group-local spike 0..127
            int sl0 = baseL + sl;
            if (sl0 < cntc) {
                int n = sl >> 3, jj = sl & 7;
                float ts = st[n * EPC + (WARM + 1) + jj].x;
                int tnext;
                if (sl0 + 1 >= cntc) tnext = (b == NCH) ? T_LEN : s_fs;
                else if (sl + 1 < GSP) {
                    int n2 = (sl + 1) >> 3, j2 = (sl + 1) & 7;
                    tnext = (int)st[n2 * EPC + (WARM + 1) + j2].x;
                } else tnext = spk_ld(spk, c * 1024 + sl0 + 1);
                float2 abv = *(const float2*)&ab[2 * sl];
                int tsi = (int)ts;
                for (int t = tsi; t < tnext; ++t)
                    out[t] = fmaf(abv.y, (float)(t - tsi) * 0.0078125f, abv.x);
            }
        }
    }

    // ---- N total (tail work, one block, off the critical path) ----
    if (b == NCH && tid < 64) {
        int s = 0;
        for (int k = 0; k < 8; ++k) s += wait_cnt(flags, lane * 8 + k);
        for (int d = 32; d; d >>= 1) s += __shfl_down(s, d, 64);
        if (lane == 0 && T_LEN < out_size) out[T_LEN] = (float)s;
    }
}

extern "C" void kernel_launch(void* const* d_in, const int* in_sizes, int n_in,
                              void* d_out, int out_size, void* d_ws, size_t ws_size,
                              hipStream_t stream)
{
    const float* x   = (const float*)d_in[0];
    const float* Wih = (const float*)d_in[1];
    const float* Whh = (const float*)d_in[2];
    const float* bih = (const float*)d_in[3];
    const float* bhh = (const float*)d_in[4];
    const float* Wv  = (const float*)d_in[5];
    const float* bv  = (const float*)d_in[6];
    const float* Wsc = (const float*)d_in[7];
    const float* bs  = (const float*)d_in[8];
    float* out = (float*)d_out;

    char* ws = (char*)d_ws;
    int* flags = (int*)(ws + OFF_FLAG);
    int* spk   = (int*)(ws + OFF_SPK);

    k_all<<<NCH + 1, 256, 0, stream>>>(x, Wih, Whh, bih, bhh, Wv, bv, Wsc, bs,
                                       out, out_size, spk, flags);
}

// Round 11
// 100.329 us; speedup vs baseline: 1.3208x; 1.0164x over previous
//
#include <hip/hip_runtime.h>
#include <stdint.h>

#define T_LEN 524288
#define SEG 8
#define WARM 8
#define EPC (SEG + WARM + 1)   // 17 staged (t,x) entries per chain
#define CHAINS 16
#define GSP (CHAINS * SEG)     // 128 spikes per wave sub-group
#define NCH 512                // chunks (1024 t each)

typedef short short8 __attribute__((ext_vector_type(8)));
typedef float f4 __attribute__((ext_vector_type(4)));
#define KEEPA(v) asm volatile("" : "+v"(v))

// ---- workspace layout (bytes) ----
static const size_t OFF_FLAG = 4096;       // 1024 int (pairs, cnt embedded)
static const size_t OFF_SPK  = 16384;      // 512*1024 int (chunk-local spike times)

__device__ __forceinline__ short bfr(float f) {        // fp32 -> bf16 RNE
    uint32_t u = __float_as_uint(f);
    u = (u + 0x7fffu + ((u >> 16) & 1u)) >> 16;
    return (short)u;
}

// padded LDS index: +1 word per 32 -> lane-stride-4 accesses are 2 lanes/bank (free)
#define IDX(j) ((j) + ((j) >> 5))

// ---- coherent handoff (no fences, no L2 wb/inv):
// flag pair carries cnt in low 11 bits; f2 = ~f1 (poison fill v,v can never match).
__device__ __forceinline__ unsigned flaghi(int c) {
    return (0x51AB7E3Du ^ ((unsigned)c * 2654435761u)) & ~0x7FFu;
}
__device__ __forceinline__ int wait_cnt(int* flags, int c) {
    const unsigned hi = flaghi(c);
    for (;;) {
        int f1 = __hip_atomic_load(&flags[2 * c],     __ATOMIC_RELAXED, __HIP_MEMORY_SCOPE_AGENT);
        int f2 = __hip_atomic_load(&flags[2 * c + 1], __ATOMIC_RELAXED, __HIP_MEMORY_SCOPE_AGENT);
        if (((unsigned)f1 & ~0x7FFu) == hi && f2 == ~f1) return f1 & 0x7FF;
        __builtin_amdgcn_s_sleep(2);
    }
}
__device__ __forceinline__ int spk_ld(const int* spk, int idx) {
    return __hip_atomic_load((int*)&spk[idx], __ATOMIC_RELAXED, __HIP_MEMORY_SCOPE_AGENT);
}

struct MaskSM  { float tile[1190]; float cs2[1190]; float wsum[4]; int wtot[4]; };
struct ChainSM { float2 st[4][CHAINS * EPC]; unsigned hx[4][CHAINS * 20]; float ab[4][2 * GSP]; };
union  SMU     { MaskSM m; ChainSM c; };

// ---- single fused kernel: block b masks chunk b, chains chunk b-1 ----
// Cross-block deps point strictly BACKWARD (flags b-5..b-1) -> deadlock-free
// under in-order dispatch at any residency. All cross-block data (spk, cnt)
// moves through agent-scope relaxed atomics => NO threadfence, NO L2 wb/inv.
// R11: latency micro-fixes -- parallel flag polls, batched staging loads,
// weight loads hoisted under the wait, tail N-sum on its own wave.
__global__ __attribute__((amdgpu_waves_per_eu(2)))
__launch_bounds__(256)
void k_all(const float* __restrict__ x,  const float* __restrict__ Wih,
           const float* __restrict__ Whh, const float* __restrict__ bih,
           const float* __restrict__ bhh, const float* __restrict__ Wv,
           const float* __restrict__ bv,  const float* __restrict__ Wsc,
           const float* __restrict__ bs,  float* __restrict__ out, int out_size,
           int* __restrict__ spk, int* __restrict__ flags)
{
    __shared__ SMU sm;
    __shared__ int s_fs;                    // first spike time of OWN chunk b
    __shared__ int cnt_sh[5];               // decoded cnts for chunks lo..c
    const int b = blockIdx.x;
    const int tid = threadIdx.x;
    const int lane = tid & 63, w4 = tid >> 6;

    if (tid == 0) s_fs = T_LEN;
    int cntb = 0;                           // own-chunk count (tid0 only)

    // ================= phase A: mask + local scatter for chunk b =================
    if (b < NCH) {
        const int bs_ = b * 1024;
        for (int j = tid; j < 1154; j += 256) {
            int g = bs_ - 130 + j;
            sm.m.tile[IDX(j)] = (g >= 0) ? x[g] : 0.f;
        }
        __syncthreads();

        const int j0 = tid * 5;
        float p[5]; float run = 0.f;
        #pragma unroll
        for (int k = 0; k < 5; ++k) {
            float v = (j0 + k < 1154) ? sm.m.tile[IDX(j0 + k)] : 0.f;
            run = fmaf(v, v, run);
            p[k] = run;
        }
        float incl = run;
        for (int d = 1; d < 64; d <<= 1) {
            float u = __shfl_up(incl, d, 64);
            if (lane >= d) incl += u;
        }
        if (lane == 63) sm.m.wsum[w4] = incl;
        __syncthreads();
        float base = incl - run;
        for (int i = 0; i < w4; ++i) base += sm.m.wsum[i];
        #pragma unroll
        for (int k = 0; k < 5; ++k)
            if (j0 + k < 1154) sm.m.cs2[IDX(j0 + k)] = base + p[k];
        __syncthreads();

        const int loc = tid * 4;
        float tv[6];
        #pragma unroll
        for (int q = 0; q < 6; ++q) tv[q] = sm.m.tile[IDX(loc + 128 + q)];
        float4 mf; int mbit[4]; int msum = 0;
        float* fp = &mf.x;
        #pragma unroll
        for (int it = 0; it < 4; ++it) {
            int t = bs_ + loc + it;
            int cdiv = t < 128 ? (t < 1 ? 1 : t) : 128;
            float s = sm.m.cs2[IDX(loc + 129 + it)] - sm.m.cs2[IDX(loc + 1 + it)];
            float rms = sqrtf(fmaxf(s, 0.f) / (float)cdiv) + 1e-8f;
            float xt = tv[it + 2];
            float pr = 2.f * tv[it + 1] - tv[it];
            bool m = (t < 2) || (fabsf(xt - pr) > 2.5f * rms);
            mbit[it] = m ? 1 : 0; fp[it] = m ? 1.f : 0.f; msum += m ? 1 : 0;
        }
        int oi = T_LEN + 1 + bs_ + loc;
        if (oi + 3 < out_size) *(float4*)(out + oi) = mf;

        int e1 = mbit[0], e2 = mbit[0] + mbit[1], e3 = e2 + mbit[2];
        int incs = msum;
        for (int d = 1; d < 64; d <<= 1) {
            int u = __shfl_up(incs, d, 64);
            if (lane >= d) incs += u;
        }
        if (lane == 63) sm.m.wtot[w4] = incs;
        __syncthreads();
        int woff = 0;
        for (int i = 0; i < w4; ++i) woff += sm.m.wtot[i];
        int texcl = woff + incs - msum;
        int ee[4] = {0, e1, e2, e3};
        int sbase = b * 1024 + texcl;
        #pragma unroll
        for (int k = 0; k < 4; ++k)
            if (mbit[k])
                __hip_atomic_store(&spk[sbase + ee[k]], bs_ + loc + k,
                                   __ATOMIC_RELAXED, __HIP_MEMORY_SCOPE_AGENT);
        if (msum > 0 && texcl == 0) {       // exactly one thread: the first spiker
            int fk = mbit[0] ? 0 : mbit[1] ? 1 : mbit[2] ? 2 : 3;
            s_fs = bs_ + loc + fk;
        }
        if (tid == 0)
            cntb = sm.m.wtot[0] + sm.m.wtot[1] + sm.m.wtot[2] + sm.m.wtot[3];
        __syncthreads();                    // drains vmcnt(0): all spk stores at coherence pt
        if (tid == 0) {
            int f1 = (int)(flaghi(b) | (unsigned)cntb);
            __hip_atomic_store(&flags[2 * b],     f1,  __ATOMIC_RELAXED, __HIP_MEMORY_SCOPE_AGENT);
            __hip_atomic_store(&flags[2 * b + 1], ~f1, __ATOMIC_RELAXED, __HIP_MEMORY_SCOPE_AGENT);
        }
    }
    if (b == 0) return;

    // ================= phase B: chains for chunk c = b-1 =================
    const int c = b - 1;
    const int lo = (c - 4 > 0) ? c - 4 : 0;
    const int nc = c - lo + 1;
    const int m = lane & 15, quad = lane >> 4;

    // ---- weight fragments hoisted ABOVE the flag wait (no dependency):
    //      their VMEM latency hides under the coherence-point polls.
    short8 A1[6], A2[6], A3;
    #pragma unroll
    for (int t = 0; t < 6; ++t) {
        union { short s[8]; short8 v; } u1, u2;
        int rowg = 16 * t + m;
        #pragma unroll
        for (int j = 0; j < 8; ++j) {
            int k = 8 * quad + j;
            u1.s[j] = bfr(Whh[rowg * 32 + k]);
            float a2v = 0.f;
            if (k == 0) a2v = Wih[rowg * 2];
            else if (k == 1) a2v = Wih[rowg * 2 + 1];
            else if (k == 2) a2v = (rowg < 64) ? (bih[rowg] + bhh[rowg]) : bih[rowg];
            u2.s[j] = bfr(a2v);
        }
        A1[t] = u1.v; A2[t] = u2.v;
    }
    {
        union { short s[8]; short8 v; } u3;
        #pragma unroll
        for (int j = 0; j < 8; ++j) {
            int k = 8 * quad + j;
            float v = (m == 0) ? Wv[k] : (m == 1) ? Wsc[k] : 0.f;
            u3.s[j] = bfr(v);
        }
        A3 = u3.v;
    }
    float bn0[4], bn1[4];
    #pragma unroll
    for (int e = 0; e < 4; ++e) {
        int r0 = quad * 4 + e;
        bn0[e] = bhh[64 + r0];  bn1[e] = bhh[80 + r0];
    }
    const float bv0 = bv[0], bs0 = bs[0];

    // ---- parallel flag polls: one lane per producer chunk (max, not sum) ----
    if (tid < 64 && lane < nc)
        cnt_sh[lane] = wait_cnt(flags, lo + lane);
    __syncthreads();                        // union transition + cnt_sh visibility

    const int cntc = cnt_sh[c - lo];
    const int baseL = 128 * w4;             // this wave's sub-group of chunk c

    if (b <= NCH && baseL < cntc) {
        float2*   st = sm.c.st[w4];
        unsigned* hx = sm.c.hx[w4];
        float*    ab = sm.c.ab[w4];

        #pragma unroll
        for (int t = 0; t < 6; ++t) { KEEPA(A1[t]); KEEPA(A2[t]); }
        KEEPA(A3);

        // ---- staging, batched for ILP: all spk loads -> all x loads -> writes ----
        int   tsv[5];
        float xsv[5];
        #pragma unroll
        for (int it = 0; it < 5; ++it) {
            int e = lane + 64 * it;
            if (e < CHAINS * EPC) {
                int n = e / EPC, j = e - n * EPC;
                int l = baseL + n * SEG - (WARM + 1) + j;
                int cc = c, ll = l;
                while (ll < 0 && cc > lo) { --cc; ll += cnt_sh[cc - lo]; }
                if (ll < 0) ll = 0;             // global-start clamp (spike 0, t=0)
                int cm = cnt_sh[cc - lo];
                if (ll >= cm) ll = cm - 1;      // tail clamp: guarded-inactive outputs only
                tsv[it] = spk_ld(spk, cc * 1024 + ll);
            }
        }
        #pragma unroll
        for (int it = 0; it < 5; ++it) {
            int e = lane + 64 * it;
            if (e < CHAINS * EPC) xsv[it] = x[tsv[it]];
        }
        #pragma unroll
        for (int it = 0; it < 5; ++it) {
            int e = lane + 64 * it;
            if (e < CHAINS * EPC) st[e] = make_float2((float)tsv[it], xsv[it]);
        }
        __builtin_amdgcn_wave_barrier();

        float h0[4], h1[4];
        #pragma unroll
        for (int e = 0; e < 4; ++e) { h0[e] = 0.f; h1[e] = 0.f; }
        short8 B1 = (short8)0;
        float tprev = st[m * EPC].x;

        for (int j = 0; j < SEG + WARM; ++j) {
            float2 cur = st[m * EPC + j + 1];   // 4 lanes/chain same addr: broadcast
            float xt = cur.y;
            float d = (cur.x - tprev) * 0.0078125f;
            tprev = cur.x;

            unsigned p0 = (__float_as_uint(d) & 0xFFFF0000u) | (__float_as_uint(xt) >> 16);
            unsigned p1 = 0x00003F80u;
            p0 = (quad == 0) ? p0 : 0u;
            p1 = (quad == 0) ? p1 : 0u;
            union { unsigned u[4]; short8 v; } b2u;
            b2u.u[0] = p0; b2u.u[1] = p1; b2u.u[2] = 0u; b2u.u[3] = 0u;
            short8 B2 = b2u.v;

            f4 z4 = {0.f, 0.f, 0.f, 0.f};
            f4 Drz[4], Dh0, Dh1, Di0, Di1;
            f4 tmp0 = __builtin_amdgcn_mfma_f32_16x16x32_bf16(A2[0], B2, z4, 0, 0, 0);
            f4 tmp1 = __builtin_amdgcn_mfma_f32_16x16x32_bf16(A2[1], B2, z4, 0, 0, 0);
            f4 tmp2 = __builtin_amdgcn_mfma_f32_16x16x32_bf16(A2[2], B2, z4, 0, 0, 0);
            f4 tmp3 = __builtin_amdgcn_mfma_f32_16x16x32_bf16(A2[3], B2, z4, 0, 0, 0);
            Di0 = __builtin_amdgcn_mfma_f32_16x16x32_bf16(A2[4], B2, z4, 0, 0, 0);
            Di1 = __builtin_amdgcn_mfma_f32_16x16x32_bf16(A2[5], B2, z4, 0, 0, 0);
            Drz[0] = __builtin_amdgcn_mfma_f32_16x16x32_bf16(A1[0], B1, tmp0, 0, 0, 0);
            Drz[1] = __builtin_amdgcn_mfma_f32_16x16x32_bf16(A1[1], B1, tmp1, 0, 0, 0);
            Drz[2] = __builtin_amdgcn_mfma_f32_16x16x32_bf16(A1[2], B1, tmp2, 0, 0, 0);
            Drz[3] = __builtin_amdgcn_mfma_f32_16x16x32_bf16(A1[3], B1, tmp3, 0, 0, 0);
            Dh0 = __builtin_amdgcn_mfma_f32_16x16x32_bf16(A1[4], B1, z4, 0, 0, 0);
            Dh1 = __builtin_amdgcn_mfma_f32_16x16x32_bf16(A1[5], B1, z4, 0, 0, 0);

            #pragma unroll
            for (int e = 0; e < 4; ++e) {
                float r0 = __builtin_amdgcn_rcpf(1.f + __builtin_amdgcn_exp2f(-1.44269504089f * Drz[0][e]));
                float r1 = __builtin_amdgcn_rcpf(1.f + __builtin_amdgcn_exp2f(-1.44269504089f * Drz[1][e]));
                float zz0 = __builtin_amdgcn_rcpf(1.f + __builtin_amdgcn_exp2f(-1.44269504089f * Drz[2][e]));
                float zz1 = __builtin_amdgcn_rcpf(1.f + __builtin_amdgcn_exp2f(-1.44269504089f * Drz[3][e]));
                float np0 = fmaf(r0, Dh0[e] + bn0[e], Di0[e]);
                float np1 = fmaf(r1, Dh1[e] + bn1[e], Di1[e]);
                float en0 = __builtin_amdgcn_exp2f(2.88539008178f * np0);
                float en1 = __builtin_amdgcn_exp2f(2.88539008178f * np1);
                float n0 = fmaf(-2.f, __builtin_amdgcn_rcpf(1.f + en0), 1.f);
                float n1 = fmaf(-2.f, __builtin_amdgcn_rcpf(1.f + en1), 1.f);
                h0[e] = fmaf(zz0, h0[e] - n0, n0);
                h1[e] = fmaf(zz1, h1[e] - n1, n1);
            }

            unsigned q0 = (__float_as_uint(h0[1]) & 0xFFFF0000u) | (__float_as_uint(h0[0]) >> 16);
            unsigned q1 = (__float_as_uint(h0[3]) & 0xFFFF0000u) | (__float_as_uint(h0[2]) >> 16);
            unsigned q2 = (__float_as_uint(h1[1]) & 0xFFFF0000u) | (__float_as_uint(h1[0]) >> 16);
            unsigned q3 = (__float_as_uint(h1[3]) & 0xFFFF0000u) | (__float_as_uint(h1[2]) >> 16);
            *(uint2*)&hx[m * 20 + 2 * quad]     = make_uint2(q0, q1);
            *(uint2*)&hx[m * 20 + 8 + 2 * quad] = make_uint2(q2, q3);
            __builtin_amdgcn_wave_barrier();
            union { uint4 u; short8 v; } bu;
            bu.u = *(const uint4*)&hx[m * 20 + 4 * quad];
            B1 = bu.v;

            if (j >= WARM) {
                f4 Dab = __builtin_amdgcn_mfma_f32_16x16x32_bf16(A3, B1, z4, 0, 0, 0);
                if (quad == 0) {
                    int lsg = baseL + m * SEG + (j - WARM);
                    if (lsg < cntc)
                        *(float2*)&ab[2 * (m * SEG + j - WARM)] =
                            make_float2(Dab[0] + bv0, Dab[1] + bs0);
                }
            }
        }
        __builtin_amdgcn_wave_barrier();

        // ---- expansion: local spike sl0 fills out[t] for t in [t_s, t_next) ----
        #pragma unroll
        for (int h = 0; h < 2; ++h) {
            int sl = lane + 64 * h;               // sub-group-local spike 0..127
            int sl0 = baseL + sl;
            if (sl0 < cntc) {
                int n = sl >> 3, jj = sl & 7;
                float ts = st[n * EPC + (WARM + 1) + jj].x;
                int tnext;
                if (sl0 + 1 >= cntc) tnext = (b == NCH) ? T_LEN : s_fs;
                else if (sl + 1 < GSP) {
                    int n2 = (sl + 1) >> 3, j2 = (sl + 1) & 7;
                    tnext = (int)st[n2 * EPC + (WARM + 1) + j2].x;
                } else tnext = spk_ld(spk, c * 1024 + sl0 + 1);
                float2 abv = *(const float2*)&ab[2 * sl];
                int tsi = (int)ts;
                for (int t = tsi; t < tnext; ++t)
                    out[t] = fmaf(abv.y, (float)(t - tsi) * 0.0078125f, abv.x);
            }
        }
    }

    // ---- N total: wave 3 of tail block, concurrent with wave 0's chain ----
    if (b == NCH && w4 == 3) {
        int s = 0;
        for (int k = 0; k < 8; ++k) s += wait_cnt(flags, lane * 8 + k);
        for (int d = 32; d; d >>= 1) s += __shfl_down(s, d, 64);
        if (lane == 0 && T_LEN < out_size) out[T_LEN] = (float)s;
    }
}

extern "C" void kernel_launch(void* const* d_in, const int* in_sizes, int n_in,
                              void* d_out, int out_size, void* d_ws, size_t ws_size,
                              hipStream_t stream)
{
    const float* x   = (const float*)d_in[0];
    const float* Wih = (const float*)d_in[1];
    const float* Whh = (const float*)d_in[2];
    const float* bih = (const float*)d_in[3];
    const float* bhh = (const float*)d_in[4];
    const float* Wv  = (const float*)d_in[5];
    const float* bv  = (const float*)d_in[6];
    const float* Wsc = (const float*)d_in[7];
    const float* bs  = (const float*)d_in[8];
    float* out = (float*)d_out;

    char* ws = (char*)d_ws;
    int* flags = (int*)(ws + OFF_FLAG);
    int* spk   = (int*)(ws + OFF_SPK);

    k_all<<<NCH + 1, 256, 0, stream>>>(x, Wih, Whh, bih, bhh, Wv, bv, Wsc, bs,
                                       out, out_size, spk, flags);
}